// Round 6
// baseline (1305.013 us; speedup 1.0000x reference)
//
#include <hip/hip_runtime.h>
#include <math.h>

#define NN 20000
#define NE 320000

typedef const float* fp;
typedef short short8 __attribute__((ext_vector_type(8)));
typedef float f32x4 __attribute__((ext_vector_type(4)));

__device__ __forceinline__ short F2B(float f) {
    unsigned u = __float_as_uint(f);
    return (short)((u + 0x7fffu + ((u >> 16) & 1u)) >> 16);
}
__device__ __forceinline__ float B2F(short s) {
    return __uint_as_float(((unsigned)(unsigned short)s) << 16);
}
__device__ __forceinline__ float siluf(float v) { return v / (1.f + __expf(-v)); }

// ---------------- weight fp32->bf16 (layout in shorts): ---------------------
// 0:      e1hh [128][256]  (e1W cols 0..255: hr|hc)
// 32768:  Wc   [128][256]  (folded radial: e1W[:,256:384] @ rW)  [k_fold]
// 65536:  e2W  [128][128]
// 81920:  c1W  [128][128]
// 98304:  c2W  [16][128] (rows 14,15 zero)
// 100352: n1W  [128][256]
// 133120: n2W  [128][128]   end 149504
__global__ void k_prep_w(fp e1W, fp e2W, fp c1W, fp c2W, fp n1W, fp n2W,
                         short* __restrict__ wb) {
    int i = blockIdx.x * 256 + threadIdx.x;
    if (i >= 149504) return;
    if (i >= 32768 && i < 65536) return;
    float v;
    if (i < 32768)       { int o = i >> 8, k = i & 255; v = e1W[o * 384 + k]; }
    else if (i < 81920)  v = e2W[i - 65536];
    else if (i < 98304)  v = c1W[i - 81920];
    else if (i < 100352) { int q = i - 98304; v = (q < 1792) ? c2W[q] : 0.f; }
    else if (i < 133120) v = n1W[i - 100352];
    else                 v = n2W[i - 133120];
    wb[i] = F2B(v);
}

__global__ void k_fold(fp e1W, fp rW, fp rB, short* __restrict__ wb,
                       float* __restrict__ bc) {
    int o = blockIdx.x, k = threadIdx.x;
    float acc = 0.f;
    for (int m = 0; m < 128; m++) acc += e1W[o * 384 + 256 + m] * rW[m * 256 + k];
    wb[32768 + o * 256 + k] = F2B(acc);
    if (k == 0) {
        float b = 0.f;
        for (int m = 0; m < 128; m++) b += e1W[o * 384 + 256 + m] * rB[m];
        bc[o] = b;
    }
}

__global__ void k_prep_h(fp h, short* __restrict__ hb) {
    int i = blockIdx.x * 256 + threadIdx.x;
    if (i < NN * 128) hb[i] = F2B(h[i]);
}

__global__ void k_node_pre(fp x, fp cw, float* __restrict__ csum, float* __restrict__ pool) {
    int n = blockIdx.x * blockDim.x + threadIdx.x;
    if (n >= NN) return;
    float cnt = 0.f, px = 0.f, py = 0.f, pz = 0.f;
#pragma unroll
    for (int c = 0; c < 14; c++) {
        float w = cw[n * 14 + c];
        if (w != 0.f) {
            cnt += 1.f;
            px += x[(n * 14 + c) * 3 + 0];
            py += x[(n * 14 + c) * 3 + 1];
            pz += x[(n * 14 + c) * 3 + 2];
        }
    }
    if (cnt < 1.f) cnt = 1.f;
    csum[n] = cnt;
    pool[n * 3 + 0] = px / cnt;
    pool[n * 3 + 1] = py / cnt;
    pool[n * 3 + 2] = pz / cnt;
}

__device__ __forceinline__ void gemm_lds(const short* __restrict__ A, int sA,
                                         const short* __restrict__ W, int Ws, int K,
                                         int mt, int nt0, int nts, f32x4* acc) {
    const int lane = threadIdx.x & 63;
    const short* ap = A + (mt * 16 + (lane & 15)) * sA + ((lane >> 4) * 8);
    for (int k0 = 0; k0 < K; k0 += 32) {
        short8 a = *(const short8*)(ap + k0);
#pragma unroll
        for (int t = 0; t < nts; t++) {
            short8 b = *(const short8*)(W + ((nt0 + t) * 16 + (lane & 15)) * Ws + k0 + ((lane >> 4) * 8));
            acc[t] = __builtin_amdgcn_mfma_f32_16x16x32_bf16(a, b, acc[t], 0, 0, 0);
        }
    }
}
__device__ __forceinline__ void gemm_grow(const short* __restrict__ arow,
                                          const short* __restrict__ W, int Ws, int K,
                                          int nt0, int nts, f32x4* acc) {
    const int lane = threadIdx.x & 63;
    for (int k0 = 0; k0 < K; k0 += 32) {
        short8 a = *(const short8*)(arow + k0);
#pragma unroll
        for (int t = 0; t < nts; t++) {
            short8 b = *(const short8*)(W + ((nt0 + t) * 16 + (lane & 15)) * Ws + k0 + ((lane >> 4) * 8));
            acc[t] = __builtin_amdgcn_mfma_f32_16x16x32_bf16(a, b, acc[t], 0, 0, 0);
        }
    }
}

// ---------------- fused edge kernel: 32 edges / block, 256 threads -----------
__global__ __launch_bounds__(256, 3) void k_edge(
    fp x, const int* __restrict__ row, const int* __restrict__ col,
    fp attr, fp cw, const short* __restrict__ hb, const short* __restrict__ wb,
    fp e1B, fp e2B, fp aW, fp aB, fp c1B, fp c2B,
    const float* __restrict__ bc, const float* __restrict__ csum,
    const float* __restrict__ poolc,
    float* __restrict__ xacc, float* __restrict__ agg,
    float* __restrict__ cntr, float* __restrict__ cntc) {
    // R1: radq [0,8448) shorts; later v1 [0,4352) | v2/c1o [4352,8704)
    __shared__ __attribute__((aligned(16))) short R1[8704];
    // transposed zero-padded attr tiles: aT[side][local edge 0..15][a*16+i]
    __shared__ __attribute__((aligned(16))) short aT[2][16][256];
    __shared__ float s_xr2[32 * 42];
    __shared__ float s_xc[16 * 42];
    __shared__ float s_cw[2][16][14];
    __shared__ float t2w[4][16 * 17];
    __shared__ int   s_r[32], s_c[32];
    __shared__ float s_inv[32];
    __shared__ float s_ch[32][14], s_pool[32][14];
    __shared__ float s_red8[32][8];
    __shared__ float s_gate[32];

    const int tid = threadIdx.x, lane = tid & 63, w = tid >> 6;
    const int bb = lane & 15, quad = lane >> 4;

    if (tid < 32) { s_r[tid] = row[blockIdx.x * 32 + tid]; s_c[tid] = col[blockIdx.x * 32 + tid]; }
    __syncthreads();

    // x_r for all 32 edges (kept for scatter phase)
    for (int p = tid; p < 32 * 42; p += 256) {
        int e = p / 42, q = p - e * 42;
        s_xr2[p] = x[(size_t)s_r[e] * 42 + q];
    }

    // ======== prep in 2 half-batches of 16 edges ========
    for (int hbi = 0; hbi < 2; hbi++) {
        __syncthreads();
        // stage attr (transposed, coalesced reads), x_c, cw
        for (int p = tid; p < 8192; p += 256) {
            int s = p >> 12, rem = p & 4095, le = rem >> 8, q = rem & 255;
            int f = q & 15, c = (q >> 4) & 15;           // source-ordered: c slow, f fast
            int node = s ? s_c[hbi * 16 + le] : s_r[hbi * 16 + le];
            float v = (c < 14) ? attr[(size_t)node * 224 + c * 16 + f] : 0.f;
            aT[s][le][f * 16 + c] = F2B(v);              // transposed [a=f][i=c]
        }
        for (int p = tid; p < 16 * 42; p += 256) {
            int le = p / 42, q = p - le * 42;
            s_xc[p] = x[(size_t)s_c[hbi * 16 + le] * 42 + q];
        }
        for (int p = tid; p < 2 * 16 * 14; p += 256) {
            int s = p / 224, rem = p - s * 224, le = rem / 14, q = rem - le * 14;
            int node = s ? s_c[hbi * 16 + le] : s_r[hbi * 16 + le];
            s_cw[s][le][q] = cw[node * 14 + q];
        }
        __syncthreads();

        // wave w: edges le = w*4 .. w*4+3 of this half-batch (all operands in LDS)
        for (int i4 = 0; i4 < 4; i4++) {
            const int le = w * 4 + i4;
            const int e = hbi * 16 + le;
            const int iic = bb < 14 ? bb : 13;
            float xr0 = s_xr2[e * 42 + iic * 3], xr1 = s_xr2[e * 42 + iic * 3 + 1],
                  xr2v = s_xr2[e * 42 + iic * 3 + 2];
            float cwri = s_cw[0][le][iic];

            // MFMA1: t2 = msg @ ac   (A: m=i, k=j computed in regs; B from aT[1])
            short8 msgv, acv;
#pragma unroll
            for (int t = 0; t < 8; t++) {
                int jj = quad * 8 + t, jc = jj < 14 ? jj : 13;
                float dx = xr0 - s_xc[le * 42 + jc * 3];
                float dy = xr1 - s_xc[le * 42 + jc * 3 + 1];
                float dz = xr2v - s_xc[le * 42 + jc * 3 + 2];
                float m = sqrtf(dx * dx + dy * dy + dz * dz) * cwri * s_cw[1][le][jc];
                msgv[t] = (bb < 14 && jj < 14) ? F2B(m) : (short)0;
            }
            if (quad < 2) acv = *(const short8*)&aT[1][le][bb * 16 + quad * 8];
            else          acv = (short8){0, 0, 0, 0, 0, 0, 0, 0};
            f32x4 t2 = (f32x4){0.f, 0.f, 0.f, 0.f};
            t2 = __builtin_amdgcn_mfma_f32_16x16x32_bf16(msgv, acv, t2, 0, 0, 0);
#pragma unroll
            for (int g = 0; g < 4; g++) t2w[w][(quad * 4 + g) * 17 + bb] = t2[g];
            __builtin_amdgcn_wave_barrier();

            // MFMA2: rad = ar^T @ t2  (A from aT[0] transposed; B = t2 via LDS)
            short8 arv, t2v;
            if (quad < 2) arv = *(const short8*)&aT[0][le][bb * 16 + quad * 8];
            else          arv = (short8){0, 0, 0, 0, 0, 0, 0, 0};
#pragma unroll
            for (int t = 0; t < 8; t++) {
                int kk = quad * 8 + t;
                t2v[t] = (kk < 16) ? F2B(t2w[w][kk * 17 + bb]) : (short)0;
            }
            f32x4 rad = (f32x4){0.f, 0.f, 0.f, 0.f};
            rad = __builtin_amdgcn_mfma_f32_16x16x32_bf16(arv, t2v, rad, 0, 0, 0);

            float ss = rad[0] * rad[0] + rad[1] * rad[1] + rad[2] * rad[2] + rad[3] * rad[3];
#pragma unroll
            for (int off = 32; off > 0; off >>= 1) ss += __shfl_xor(ss, off, 64);
            float inv = 1.f / (sqrtf(ss) + 1.f);
            if (lane == 0) s_inv[e] = inv;
#pragma unroll
            for (int g = 0; g < 4; g++)
                R1[e * 264 + (quad * 4 + g) * 16 + bb] = F2B(rad[g] * inv);
            __builtin_amdgcn_wave_barrier();
        }
    }
    __syncthreads();

    // ======== GEMM chain ========
    const int mt = w & 1, nh = w >> 1;
    const int m_ = mt * 16 + bb;
    f32x4 acc[4];
#pragma unroll
    for (int t = 0; t < 4; t++) acc[t] = (f32x4){0.f, 0.f, 0.f, 0.f};

    // e1 = silu(hr@W1 + hc@W2 + radq@Wc + e1B + bc*inv)
    {
        const short* ar_ = hb + (size_t)s_r[m_] * 128 + quad * 8;
        const short* ac_ = hb + (size_t)s_c[m_] * 128 + quad * 8;
        gemm_grow(ar_, wb, 256, 128, nh * 4, 4, acc);
        gemm_grow(ac_, wb + 128, 256, 128, nh * 4, 4, acc);
        gemm_lds(R1, 264, wb + 32768, 256, 256, mt, nh * 4, 4, acc);
    }
    __syncthreads();
    short* V1 = R1;
    short* V2 = R1 + 4352;
    short* C1O = R1 + 4352;   // aliases V2 (dead when c1o written)
#pragma unroll
    for (int t = 0; t < 4; t++)
#pragma unroll
        for (int i = 0; i < 4; i++) {
            int m = mt * 16 + quad * 4 + i, n = (nh * 4 + t) * 16 + bb;
            V1[m * 136 + n] = F2B(siluf(acc[t][i] + e1B[n] + bc[n] * s_inv[m]));
        }
    __syncthreads();

    // e2
#pragma unroll
    for (int t = 0; t < 4; t++) acc[t] = (f32x4){0.f, 0.f, 0.f, 0.f};
    gemm_lds(V1, 136, wb + 65536, 128, 128, mt, nh * 4, 4, acc);
#pragma unroll
    for (int t = 0; t < 4; t++)
#pragma unroll
        for (int i = 0; i < 4; i++) {
            int m = mt * 16 + quad * 4 + i, n = (nh * 4 + t) * 16 + bb;
            V2[m * 136 + n] = F2B(siluf(acc[t][i] + e2B[n]));
        }
    __syncthreads();

    // attention gate
    {
        int e = tid >> 3, j = tid & 7;
        float s = 0.f;
        for (int f = j * 16; f < j * 16 + 16; f++) s += B2F(V2[e * 136 + f]) * aW[f];
        s_red8[e][j] = s;
    }
    __syncthreads();
    if (tid < 32) {
        float s = 0.f;
#pragma unroll
        for (int j = 0; j < 8; j++) s += s_red8[tid][j];
        s_gate[tid] = 1.f / (1.f + __expf(-(s + aB[0])));
    }
    __syncthreads();
    for (int p = tid; p < 32 * 128; p += 256) {
        int e = p >> 7, f = p & 127;
        V1[e * 136 + f] = F2B(B2F(V2[e * 136 + f]) * s_gate[e]);  // v3 over v1
    }
    __syncthreads();

    // c1 (c1o overwrites dead v2)
#pragma unroll
    for (int t = 0; t < 4; t++) acc[t] = (f32x4){0.f, 0.f, 0.f, 0.f};
    gemm_lds(V1, 136, wb + 81920, 128, 128, mt, nh * 4, 4, acc);
    __syncthreads();
#pragma unroll
    for (int t = 0; t < 4; t++)
#pragma unroll
        for (int i = 0; i < 4; i++) {
            int m = mt * 16 + quad * 4 + i, n = (nh * 4 + t) * 16 + bb;
            C1O[m * 136 + n] = F2B(siluf(acc[t][i] + c1B[n]));
        }
    __syncthreads();

    // c2 (14 outputs; nh==0 waves)
    if (nh == 0) {
        f32x4 a4 = (f32x4){0.f, 0.f, 0.f, 0.f};
        gemm_lds(C1O, 136, wb + 98304, 128, 128, mt, 0, 1, &a4);
#pragma unroll
        for (int i = 0; i < 4; i++) {
            int m = mt * 16 + quad * 4 + i;
            if (bb < 14) s_ch[m][bb] = a4[i] + c2B[bb];
        }
    }
    __syncthreads();

    // roller pooling
    if (tid < 32) {
        int t = (int)(csum[s_r[tid]] + 0.5f) - 1;
        if (t < 0) t = 0; if (t > 13) t = 13;
        int Wd = 14 - t;
        for (int i = 0; i < 14; i++) {
            int jend = i + Wd - 1; if (jend > 13) jend = 13;
            float a = 0.f;
            for (int j = i; j <= jend; j++) a += s_ch[tid][j];
            s_pool[tid][i] = a / (float)Wd;
        }
    }
    __syncthreads();

    // scatters
    for (int p = tid; p < 32 * 42; p += 256) {
        int e = p / 42, q = p - e * 42, i = q / 3, d = q - i * 3;
        float diff = s_xr2[e * 42 + q] - poolc[s_c[e] * 3 + d];
        atomicAdd(&xacc[(size_t)s_r[e] * 42 + q], diff * s_pool[e][i]);
    }
    for (int p = tid; p < 32 * 128; p += 256) {
        int e = p >> 7, f = p & 127;
        atomicAdd(&agg[(size_t)s_c[e] * 128 + f], B2F(V1[e * 136 + f]));
    }
    if (tid < 32) {
        atomicAdd(&cntr[s_r[tid]], 1.f);
        atomicAdd(&cntc[s_c[tid]], 1.f);
    }
}

// ---------------- batched node post: 32 nodes / block ------------------------
__global__ __launch_bounds__(256, 2) void k_node_post(
    fp h, fp x, const short* __restrict__ wb,
    fp n1B, fp n2B, fp lng, fp lnb,
    const float* __restrict__ agg, const float* __restrict__ cntc,
    const float* __restrict__ xacc, const float* __restrict__ cntr,
    float* __restrict__ outh, float* __restrict__ outx) {
    __shared__ __attribute__((aligned(16))) short nA[32 * 264];
    __shared__ __attribute__((aligned(16))) short nMid[32 * 136];
    __shared__ float nY[32][128];
    __shared__ float nred8[32][8];
    __shared__ float nmu[32], nrs[32];

    const int tid = threadIdx.x;
    const int wave = tid >> 6, mt = wave & 1, nh = wave >> 1;
    const int lane = tid & 63, bb = lane & 15, quad = lane >> 4;
    const int nb0 = blockIdx.x * 32;
    const short* n1Wb = wb + 100352;
    const short* n2Wb = wb + 133120;

    for (int p = tid; p < 32 * 128; p += 256) {
        int i = p >> 7, f = p & 127;
        int n = nb0 + i;
        nA[i * 264 + f] = F2B(h[(size_t)n * 128 + f]);
        float cc = cntc[n]; if (cc < 1.f) cc = 1.f;
        nA[i * 264 + 128 + f] = F2B(agg[(size_t)n * 128 + f] / cc);
    }
    __syncthreads();

    f32x4 acc[4];
#pragma unroll
    for (int t = 0; t < 4; t++) acc[t] = (f32x4){0.f, 0.f, 0.f, 0.f};
    gemm_lds(nA, 264, n1Wb, 256, 256, mt, nh * 4, 4, acc);
#pragma unroll
    for (int t = 0; t < 4; t++)
#pragma unroll
        for (int i = 0; i < 4; i++) {
            int m = mt * 16 + quad * 4 + i, n = (nh * 4 + t) * 16 + bb;
            nMid[m * 136 + n] = F2B(siluf(acc[t][i] + n1B[n]));
        }
    __syncthreads();

#pragma unroll
    for (int t = 0; t < 4; t++) acc[t] = (f32x4){0.f, 0.f, 0.f, 0.f};
    gemm_lds(nMid, 136, n2Wb, 128, 128, mt, nh * 4, 4, acc);
#pragma unroll
    for (int t = 0; t < 4; t++)
#pragma unroll
        for (int i = 0; i < 4; i++) {
            int m = mt * 16 + quad * 4 + i, n = (nh * 4 + t) * 16 + bb;
            nY[m][n] = acc[t][i] + n2B[n] + h[(size_t)(nb0 + m) * 128 + n];
        }
    __syncthreads();

    {
        int i = tid >> 3, j = tid & 7;
        float s = 0.f;
        for (int f = j * 16; f < j * 16 + 16; f++) s += nY[i][f];
        nred8[i][j] = s;
    }
    __syncthreads();
    if (tid < 32) {
        float s = 0.f;
#pragma unroll
        for (int j = 0; j < 8; j++) s += nred8[tid][j];
        nmu[tid] = s * (1.f / 128.f);
    }
    __syncthreads();
    {
        int i = tid >> 3, j = tid & 7;
        float mu = nmu[i], s = 0.f;
        for (int f = j * 16; f < j * 16 + 16; f++) { float d = nY[i][f] - mu; s += d * d; }
        nred8[i][j] = s;
    }
    __syncthreads();
    if (tid < 32) {
        float s = 0.f;
#pragma unroll
        for (int j = 0; j < 8; j++) s += nred8[tid][j];
        nrs[tid] = rsqrtf(s * (1.f / 128.f) + 1e-5f);
    }
    __syncthreads();
    for (int p = tid; p < 32 * 128; p += 256) {
        int i = p >> 7, f = p & 127;
        outh[(size_t)(nb0 + i) * 128 + f] = (nY[i][f] - nmu[i]) * nrs[i] * lng[f] + lnb[f];
    }
    for (int p = tid; p < 32 * 42; p += 256) {
        int i = p / 42, q = p - i * 42;
        int n = nb0 + i;
        float cr = cntr[n]; if (cr < 1.f) cr = 1.f;
        outx[(size_t)n * 42 + q] = x[(size_t)n * 42 + q] + xacc[(size_t)n * 42 + q] / cr;
    }
}

extern "C" void kernel_launch(void* const* d_in, const int* in_sizes, int n_in,
                              void* d_out, int out_size, void* d_ws, size_t ws_size,
                              hipStream_t stream) {
    fp h   = (fp)d_in[0];
    fp x   = (fp)d_in[1];
    const int* row = (const int*)d_in[2];
    const int* col = (const int*)d_in[3];
    fp attr= (fp)d_in[4];
    fp cw  = (fp)d_in[5];
    fp rW  = (fp)d_in[6];  fp rB  = (fp)d_in[7];
    fp e1W = (fp)d_in[8];  fp e1B = (fp)d_in[9];
    fp e2W = (fp)d_in[10]; fp e2B = (fp)d_in[11];
    fp aW  = (fp)d_in[12]; fp aB  = (fp)d_in[13];
    fp c1W = (fp)d_in[14]; fp c1B = (fp)d_in[15];
    fp c2W = (fp)d_in[16]; fp c2B = (fp)d_in[17];
    fp n1W = (fp)d_in[18]; fp n1B = (fp)d_in[19];
    fp n2W = (fp)d_in[20]; fp n2B = (fp)d_in[21];
    fp lng = (fp)d_in[22]; fp lnb = (fp)d_in[23];

    float* ws   = (float*)d_ws;
    float* xacc = ws;
    float* agg  = ws + 840000;
    float* cntr = ws + 3400000;
    float* cntc = ws + 3420000;
    float* csum = ws + 3440000;
    float* pool = ws + 3460000;
    float* bc   = ws + 3520000;
    short* hb   = (short*)(ws + 3520128);
    short* wb   = (short*)(ws + 4800128);

    hipMemsetAsync(d_ws, 0, 3440000 * sizeof(float), stream);

    k_prep_w<<<(149504 + 255) / 256, 256, 0, stream>>>(e1W, e2W, c1W, c2W, n1W, n2W, wb);
    k_fold<<<128, 256, 0, stream>>>(e1W, rW, rB, wb, bc);
    k_prep_h<<<(NN * 128 + 255) / 256, 256, 0, stream>>>(h, hb);
    k_node_pre<<<(NN + 255) / 256, 256, 0, stream>>>(x, cw, csum, pool);

    k_edge<<<NE / 32, 256, 0, stream>>>(x, row, col, attr, cw, hb, wb,
                                        e1B, e2B, aW, aB, c1B, c2B,
                                        bc, csum, pool, xacc, agg, cntr, cntc);

    float* outh = (float*)d_out;
    float* outx = outh + NN * 128;
    k_node_post<<<NN / 32, 256, 0, stream>>>(h, x, wb, n1B, n2B, lng, lnb,
                                             agg, cntc, xacc, cntr, outh, outx);
}

// Round 7
// 1171.434 us; speedup vs baseline: 1.1140x; 1.1140x over previous
//
#include <hip/hip_runtime.h>
#include <math.h>

#define NN 20000
#define NE 320000

typedef const float* fp;
typedef short short8 __attribute__((ext_vector_type(8)));
typedef float f32x4 __attribute__((ext_vector_type(4)));

__device__ __forceinline__ short F2B(float f) {
    unsigned u = __float_as_uint(f);
    return (short)((u + 0x7fffu + ((u >> 16) & 1u)) >> 16);
}
__device__ __forceinline__ float B2F(short s) {
    return __uint_as_float(((unsigned)(unsigned short)s) << 16);
}
__device__ __forceinline__ float siluf(float v) { return v / (1.f + __expf(-v)); }

// ---------------- weight fp32->bf16 (layout in shorts): ---------------------
// 0:      e1hh [128][256]  (e1W cols 0..255: hr|hc)
// 32768:  Wc   [128][256]  (folded radial: e1W[:,256:384] @ rW)  [k_fold]
// 65536:  e2W  [128][128]
// 81920:  c1W  [128][128]
// 98304:  c2W  [16][128] (rows 14,15 zero)
// 100352: n1W  [128][256]
// 133120: n2W  [128][128]   end 149504
__global__ void k_prep_w(fp e1W, fp e2W, fp c1W, fp c2W, fp n1W, fp n2W,
                         short* __restrict__ wb) {
    int i = blockIdx.x * 256 + threadIdx.x;
    if (i >= 149504) return;
    if (i >= 32768 && i < 65536) return;
    float v;
    if (i < 32768)       { int o = i >> 8, k = i & 255; v = e1W[o * 384 + k]; }
    else if (i < 81920)  v = e2W[i - 65536];
    else if (i < 98304)  v = c1W[i - 81920];
    else if (i < 100352) { int q = i - 98304; v = (q < 1792) ? c2W[q] : 0.f; }
    else if (i < 133120) v = n1W[i - 100352];
    else                 v = n2W[i - 133120];
    wb[i] = F2B(v);
}

__global__ void k_fold(fp e1W, fp rW, fp rB, short* __restrict__ wb,
                       float* __restrict__ bc) {
    int o = blockIdx.x, k = threadIdx.x;
    float acc = 0.f;
    for (int m = 0; m < 128; m++) acc += e1W[o * 384 + 256 + m] * rW[m * 256 + k];
    wb[32768 + o * 256 + k] = F2B(acc);
    if (k == 0) {
        float b = 0.f;
        for (int m = 0; m < 128; m++) b += e1W[o * 384 + 256 + m] * rB[m];
        bc[o] = b;
    }
}

__global__ void k_prep_h(fp h, short* __restrict__ hb) {
    int i = blockIdx.x * 256 + threadIdx.x;
    if (i < NN * 128) hb[i] = F2B(h[i]);
}

__global__ void k_node_pre(fp x, fp cw, float* __restrict__ csum, float* __restrict__ pool) {
    int n = blockIdx.x * blockDim.x + threadIdx.x;
    if (n >= NN) return;
    float cnt = 0.f, px = 0.f, py = 0.f, pz = 0.f;
#pragma unroll
    for (int c = 0; c < 14; c++) {
        float w = cw[n * 14 + c];
        if (w != 0.f) {
            cnt += 1.f;
            px += x[(n * 14 + c) * 3 + 0];
            py += x[(n * 14 + c) * 3 + 1];
            pz += x[(n * 14 + c) * 3 + 2];
        }
    }
    if (cnt < 1.f) cnt = 1.f;
    csum[n] = cnt;
    pool[n * 3 + 0] = px / cnt;
    pool[n * 3 + 1] = py / cnt;
    pool[n * 3 + 2] = pz / cnt;
}

__device__ __forceinline__ void gemm_lds(const short* __restrict__ A, int sA,
                                         const short* __restrict__ W, int Ws, int K,
                                         int mt, int nt0, int nts, f32x4* acc) {
    const int lane = threadIdx.x & 63;
    const short* ap = A + (mt * 16 + (lane & 15)) * sA + ((lane >> 4) * 8);
    for (int k0 = 0; k0 < K; k0 += 32) {
        short8 a = *(const short8*)(ap + k0);
#pragma unroll
        for (int t = 0; t < nts; t++) {
            short8 b = *(const short8*)(W + ((nt0 + t) * 16 + (lane & 15)) * Ws + k0 + ((lane >> 4) * 8));
            acc[t] = __builtin_amdgcn_mfma_f32_16x16x32_bf16(a, b, acc[t], 0, 0, 0);
        }
    }
}
__device__ __forceinline__ void gemm_grow(const short* __restrict__ arow,
                                          const short* __restrict__ W, int Ws, int K,
                                          int nt0, int nts, f32x4* acc) {
    const int lane = threadIdx.x & 63;
    for (int k0 = 0; k0 < K; k0 += 32) {
        short8 a = *(const short8*)(arow + k0);
#pragma unroll
        for (int t = 0; t < nts; t++) {
            short8 b = *(const short8*)(W + ((nt0 + t) * 16 + (lane & 15)) * Ws + k0 + ((lane >> 4) * 8));
            acc[t] = __builtin_amdgcn_mfma_f32_16x16x32_bf16(a, b, acc[t], 0, 0, 0);
        }
    }
}

// ---------------- H12: per-node h@W1 | h@W2 (bf16 out) -----------------------
__global__ __launch_bounds__(256, 2) void k_hw(const short* __restrict__ hb,
                                               const short* __restrict__ wb,
                                               short* __restrict__ H12) {
    __shared__ __attribute__((aligned(16))) short A[32 * 136];
    const int tid = threadIdx.x, lane = tid & 63, w = tid >> 6;
    const int bb = lane & 15, quad = lane >> 4;
    const int mt = w & 1, nh = w >> 1, nb0 = blockIdx.x * 32;
    for (int p = tid; p < 512; p += 256) {
        int i = p >> 4, v = p & 15;
        *(short8*)(A + i * 136 + v * 8) = *(const short8*)(hb + (size_t)(nb0 + i) * 128 + v * 8);
    }
    __syncthreads();
    f32x4 acc[4];
#pragma unroll
    for (int t = 0; t < 4; t++) acc[t] = (f32x4){0.f, 0.f, 0.f, 0.f};
    gemm_lds(A, 136, wb, 256, 128, mt, nh * 4, 4, acc);
#pragma unroll
    for (int t = 0; t < 4; t++)
#pragma unroll
        for (int i = 0; i < 4; i++) {
            int m = mt * 16 + quad * 4 + i, n = (nh * 4 + t) * 16 + bb;
            H12[(size_t)(nb0 + m) * 256 + n] = F2B(acc[t][i]);
        }
#pragma unroll
    for (int t = 0; t < 4; t++) acc[t] = (f32x4){0.f, 0.f, 0.f, 0.f};
    gemm_lds(A, 136, wb + 128, 256, 128, mt, nh * 4, 4, acc);
#pragma unroll
    for (int t = 0; t < 4; t++)
#pragma unroll
        for (int i = 0; i < 4; i++) {
            int m = mt * 16 + quad * 4 + i, n = (nh * 4 + t) * 16 + bb;
            H12[(size_t)(nb0 + m) * 256 + 128 + n] = F2B(acc[t][i]);
        }
}

// ---------------- radial: wave=16 edges, no block barriers -------------------
// writes e1p[e][128] = (rad*inv)@Wc^T + inv*bc   (bf16)
__global__ __launch_bounds__(256, 4) void k_radial(
    fp x, const int* __restrict__ row, const int* __restrict__ col,
    fp attr, fp cw, const short* __restrict__ wb, const float* __restrict__ bc,
    short* __restrict__ e1p) {
    __shared__ __attribute__((aligned(16))) short Arad[4][16 * 264];
    __shared__ float xc2[4][2][42];
    __shared__ float cwc2[4][2][14];
    __shared__ float inv16[4][16];
    const int tid = threadIdx.x, lane = tid & 63, w = tid >> 6;
    const int bb = lane & 15, quad = lane >> 4;
    const int e0 = blockIdx.x * 64 + w * 16;
    const short* Wc = wb + 32768;
    short* Ar = Arad[w];

#pragma unroll 2
    for (int m = 0; m < 16; m++) {
        const int e = e0 + m;
        const int r = row[e], c = col[e];
        const int bufi = m & 1;
        if (lane < 42)      xc2[w][bufi][lane] = x[(size_t)c * 42 + lane];
        else if (lane < 56) cwc2[w][bufi][lane - 42] = cw[c * 14 + (lane - 42)];
        const int iic = bb < 14 ? bb : 13;
        float xr0 = x[(size_t)r * 42 + iic * 3];
        float xr1 = x[(size_t)r * 42 + iic * 3 + 1];
        float xr2 = x[(size_t)r * 42 + iic * 3 + 2];
        float cwr = cw[r * 14 + iic];
        short8 msgv, acv, arv;
#pragma unroll
        for (int t = 0; t < 8; t++) {
            int jj = quad * 8 + t;
            acv[t] = (jj < 14) ? F2B(attr[(size_t)c * 224 + jj * 16 + bb]) : (short)0;
            arv[t] = (jj < 14) ? F2B(attr[(size_t)r * 224 + jj * 16 + bb]) : (short)0;
        }
#pragma unroll
        for (int t = 0; t < 8; t++) {
            int jj = quad * 8 + t, jc = jj < 14 ? jj : 13;
            float dx = xr0 - xc2[w][bufi][jc * 3];
            float dy = xr1 - xc2[w][bufi][jc * 3 + 1];
            float dz = xr2 - xc2[w][bufi][jc * 3 + 2];
            float mm = sqrtf(dx * dx + dy * dy + dz * dz) * cwr * cwc2[w][bufi][jc];
            msgv[t] = (bb < 14 && jj < 14) ? F2B(mm) : (short)0;
        }
        // MFMA1: t2 = msg @ ac
        f32x4 t2 = (f32x4){0.f, 0.f, 0.f, 0.f};
        t2 = __builtin_amdgcn_mfma_f32_16x16x32_bf16(msgv, acv, t2, 0, 0, 0);
        // redistribute t2 (C-layout) -> B-fragment via shuffles (rows>=16 are zero)
        short8 t2v;
#pragma unroll
        for (int t = 0; t < 8; t++) {
            int grp = (2 * quad + (t >> 2)) & 3;
            float v = __shfl(t2[t & 3], bb + 16 * grp, 64);
            t2v[t] = (quad < 2) ? F2B(v) : (short)0;
        }
        // MFMA2: rad = ar^T @ t2
        f32x4 rad = (f32x4){0.f, 0.f, 0.f, 0.f};
        rad = __builtin_amdgcn_mfma_f32_16x16x32_bf16(arv, t2v, rad, 0, 0, 0);
        float ss = rad[0] * rad[0] + rad[1] * rad[1] + rad[2] * rad[2] + rad[3] * rad[3];
#pragma unroll
        for (int off = 32; off > 0; off >>= 1) ss += __shfl_xor(ss, off, 64);
        float inv = 1.f / (sqrtf(ss) + 1.f);
        if (lane == 0) inv16[w][m] = inv;
#pragma unroll
        for (int g = 0; g < 4; g++)
            Ar[m * 264 + (quad * 4 + g) * 16 + bb] = F2B(rad[g] * inv);
    }
    __builtin_amdgcn_wave_barrier();

    // GEMM: [16x256] @ Wc^T -> [16x128]
    f32x4 acc[8];
#pragma unroll
    for (int t = 0; t < 8; t++) acc[t] = (f32x4){0.f, 0.f, 0.f, 0.f};
    for (int k0 = 0; k0 < 256; k0 += 32) {
        short8 a = *(const short8*)(Ar + bb * 264 + k0 + quad * 8);
#pragma unroll
        for (int t = 0; t < 8; t++) {
            short8 b = *(const short8*)(Wc + (t * 16 + bb) * 256 + k0 + quad * 8);
            acc[t] = __builtin_amdgcn_mfma_f32_16x16x32_bf16(a, b, acc[t], 0, 0, 0);
        }
    }
    // epilogue: stage to LDS (reuse Ar), then coalesced global write
    short* E1 = Ar;
#pragma unroll
    for (int t = 0; t < 8; t++)
#pragma unroll
        for (int i = 0; i < 4; i++) {
            int m = quad * 4 + i, n = t * 16 + bb;
            E1[m * 136 + n] = F2B(acc[t][i] + inv16[w][m] * bc[n]);
        }
    __builtin_amdgcn_wave_barrier();
    for (int p = lane; p < 256; p += 64) {
        int m = p >> 4, v = p & 15;
        *(short8*)(e1p + (size_t)(e0 + m) * 128 + v * 8) = *(const short8*)(E1 + m * 136 + v * 8);
    }
}

// ---------------- slim fused edge kernel (split path) ------------------------
__global__ __launch_bounds__(256, 6) void k_edge_split(
    fp x, const int* __restrict__ row, const int* __restrict__ col,
    const short* __restrict__ H12, const short* __restrict__ e1p,
    const short* __restrict__ wb,
    fp e1B, fp e2B, fp aW, fp aB, fp c1B, fp c2B,
    const float* __restrict__ csum, const float* __restrict__ poolc,
    float* __restrict__ xacc, float* __restrict__ agg,
    float* __restrict__ cntr, float* __restrict__ cntc) {
    __shared__ __attribute__((aligned(16))) short V1[32 * 136];
    __shared__ __attribute__((aligned(16))) short V2[32 * 136];  // also c1o
    __shared__ int s_r[32], s_c[32];
    __shared__ float s_ch[32][14], s_pool[32][14];
    __shared__ float s_red8[32][8], s_gate[32];

    const int tid = threadIdx.x, lane = tid & 63, w = tid >> 6;
    const int bb = lane & 15, quad = lane >> 4;
    const int mt = w & 1, nh = w >> 1;
    const int e0 = blockIdx.x * 32;

    if (tid < 32) { s_r[tid] = row[e0 + tid]; s_c[tid] = col[e0 + tid]; }
    __syncthreads();

    // V1 = silu(H1[r] + H2[c] + e1p + e1B)
    for (int p = tid; p < 512; p += 256) {
        int e = p >> 4, v = p & 15;
        short8 hr = *(const short8*)(H12 + (size_t)s_r[e] * 256 + v * 8);
        short8 hc = *(const short8*)(H12 + (size_t)s_c[e] * 256 + 128 + v * 8);
        short8 pp = *(const short8*)(e1p + (size_t)(e0 + e) * 128 + v * 8);
        short8 o;
#pragma unroll
        for (int j = 0; j < 8; j++)
            o[j] = F2B(siluf(B2F(hr[j]) + B2F(hc[j]) + B2F(pp[j]) + e1B[v * 8 + j]));
        *(short8*)(V1 + e * 136 + v * 8) = o;
    }
    __syncthreads();

    // e2
    f32x4 acc[4];
#pragma unroll
    for (int t = 0; t < 4; t++) acc[t] = (f32x4){0.f, 0.f, 0.f, 0.f};
    gemm_lds(V1, 136, wb + 65536, 128, 128, mt, nh * 4, 4, acc);
#pragma unroll
    for (int t = 0; t < 4; t++)
#pragma unroll
        for (int i = 0; i < 4; i++) {
            int m = mt * 16 + quad * 4 + i, n = (nh * 4 + t) * 16 + bb;
            V2[m * 136 + n] = F2B(siluf(acc[t][i] + e2B[n]));
        }
    __syncthreads();

    // attention gate
    {
        int e = tid >> 3, j = tid & 7;
        float s = 0.f;
        for (int f = j * 16; f < j * 16 + 16; f++) s += B2F(V2[e * 136 + f]) * aW[f];
        s_red8[e][j] = s;
    }
    __syncthreads();
    if (tid < 32) {
        float s = 0.f;
#pragma unroll
        for (int j = 0; j < 8; j++) s += s_red8[tid][j];
        s_gate[tid] = 1.f / (1.f + __expf(-(s + aB[0])));
    }
    __syncthreads();
    for (int p = tid; p < 32 * 128; p += 256) {
        int e = p >> 7, f = p & 127;
        V1[e * 136 + f] = F2B(B2F(V2[e * 136 + f]) * s_gate[e]);  // v3 over v1
    }
    __syncthreads();

    // c1 (into V2 region; v2 dead)
#pragma unroll
    for (int t = 0; t < 4; t++) acc[t] = (f32x4){0.f, 0.f, 0.f, 0.f};
    gemm_lds(V1, 136, wb + 81920, 128, 128, mt, nh * 4, 4, acc);
    __syncthreads();
#pragma unroll
    for (int t = 0; t < 4; t++)
#pragma unroll
        for (int i = 0; i < 4; i++) {
            int m = mt * 16 + quad * 4 + i, n = (nh * 4 + t) * 16 + bb;
            V2[m * 136 + n] = F2B(siluf(acc[t][i] + c1B[n]));
        }
    __syncthreads();

    // c2
    if (nh == 0) {
        f32x4 a4 = (f32x4){0.f, 0.f, 0.f, 0.f};
        gemm_lds(V2, 136, wb + 98304, 128, 128, mt, 0, 1, &a4);
#pragma unroll
        for (int i = 0; i < 4; i++) {
            int m = mt * 16 + quad * 4 + i;
            if (bb < 14) s_ch[m][bb] = a4[i] + c2B[bb];
        }
    }
    __syncthreads();

    // roller pooling
    if (tid < 32) {
        int t = (int)(csum[s_r[tid]] + 0.5f) - 1;
        if (t < 0) t = 0; if (t > 13) t = 13;
        int Wd = 14 - t;
        for (int i = 0; i < 14; i++) {
            int jend = i + Wd - 1; if (jend > 13) jend = 13;
            float a = 0.f;
            for (int j = i; j <= jend; j++) a += s_ch[tid][j];
            s_pool[tid][i] = a / (float)Wd;
        }
    }
    __syncthreads();

    // scatters
    for (int p = tid; p < 32 * 42; p += 256) {
        int e = p / 42, q = p - e * 42, i = q / 3, d = q - i * 3;
        float diff = x[(size_t)s_r[e] * 42 + q] - poolc[s_c[e] * 3 + d];
        atomicAdd(&xacc[(size_t)s_r[e] * 42 + q], diff * s_pool[e][i]);
    }
    for (int p = tid; p < 32 * 128; p += 256) {
        int e = p >> 7, f = p & 127;
        atomicAdd(&agg[(size_t)s_c[e] * 128 + f], B2F(V1[e * 136 + f]));
    }
    if (tid < 32) {
        atomicAdd(&cntr[s_r[tid]], 1.f);
        atomicAdd(&cntc[s_c[tid]], 1.f);
    }
}

// ---------------- fused fallback (round-5 kernel) ----------------------------
__global__ __launch_bounds__(256, 3) void k_edge_fused(
    fp x, const int* __restrict__ row, const int* __restrict__ col,
    fp attr, fp cw, const short* __restrict__ hb, const short* __restrict__ wb,
    fp e1B, fp e2B, fp aW, fp aB, fp c1B, fp c2B,
    const float* __restrict__ bc, const float* __restrict__ csum,
    const float* __restrict__ poolc,
    float* __restrict__ xacc, float* __restrict__ agg,
    float* __restrict__ cntr, float* __restrict__ cntc) {
    __shared__ __attribute__((aligned(16))) short R1[13056];
    __shared__ float s_xr2[32 * 42];
    __shared__ float T[4][352];
    __shared__ int   s_r[32], s_c[32];
    __shared__ float s_inv[32];
    __shared__ float s_ch[32][14], s_pool[32][14];
    __shared__ float s_red8[32][8];
    __shared__ float s_gate[32];

    const int tid = threadIdx.x, lane = tid & 63, w = tid >> 6;
    const int bb = lane & 15, quad = lane >> 4;

    if (tid < 32) { s_r[tid] = row[blockIdx.x * 32 + tid]; s_c[tid] = col[blockIdx.x * 32 + tid]; }
    __syncthreads();

    float* slot = T[w];
    float* t2w = slot + 72;
    for (int i8 = 0; i8 < 8; i8++) {
        const int e = w * 8 + i8;
        const int r = s_r[e], cl = s_c[e];
        if (lane < 42) {
            s_xr2[e * 42 + lane] = x[(size_t)r * 42 + lane];
            slot[lane] = x[(size_t)cl * 42 + lane];
        }
        if (lane < 14)      slot[42 + lane] = cw[r * 14 + lane];
        else if (lane < 28) slot[56 + (lane - 14)] = cw[cl * 14 + (lane - 14)];
        __builtin_amdgcn_wave_barrier();

        const int iic = bb < 14 ? bb : 13;
        float xr0 = s_xr2[e * 42 + iic * 3], xr1 = s_xr2[e * 42 + iic * 3 + 1],
              xr2v = s_xr2[e * 42 + iic * 3 + 2];
        float cwri = slot[42 + iic];
        short8 msgv, acv;
#pragma unroll
        for (int t = 0; t < 8; t++) {
            int jj = quad * 8 + t, jc = jj < 14 ? jj : 13;
            float dx = xr0 - slot[jc * 3], dy = xr1 - slot[jc * 3 + 1], dz = xr2v - slot[jc * 3 + 2];
            float m = sqrtf(dx * dx + dy * dy + dz * dz) * cwri * slot[56 + jc];
            msgv[t] = (bb < 14 && jj < 14) ? F2B(m) : (short)0;
            acv[t] = F2B(attr[(size_t)cl * 224 + jc * 16 + bb]);
        }
        f32x4 t2 = (f32x4){0.f, 0.f, 0.f, 0.f};
        t2 = __builtin_amdgcn_mfma_f32_16x16x32_bf16(msgv, acv, t2, 0, 0, 0);
#pragma unroll
        for (int g = 0; g < 4; g++) t2w[(quad * 4 + g) * 17 + bb] = t2[g];
        __builtin_amdgcn_wave_barrier();

        short8 arv, t2v;
#pragma unroll
        for (int t = 0; t < 8; t++) {
            int kk = quad * 8 + t, kc = kk < 16 ? kk : 15;
            t2v[t] = F2B(t2w[kc * 17 + bb]);
            arv[t] = (kk < 14) ? F2B(attr[(size_t)r * 224 + kk * 16 + bb]) : (short)0;
        }
        f32x4 rad = (f32x4){0.f, 0.f, 0.f, 0.f};
        rad = __builtin_amdgcn_mfma_f32_16x16x32_bf16(arv, t2v, rad, 0, 0, 0);

        float ss = rad[0] * rad[0] + rad[1] * rad[1] + rad[2] * rad[2] + rad[3] * rad[3];
#pragma unroll
        for (int off = 32; off > 0; off >>= 1) ss += __shfl_xor(ss, off, 64);
        float inv = 1.f / (sqrtf(ss) + 1.f);
        if (lane == 0) s_inv[e] = inv;
#pragma unroll
        for (int g = 0; g < 4; g++)
            R1[e * 264 + (quad * 4 + g) * 16 + bb] = F2B(rad[g] * inv);
        __builtin_amdgcn_wave_barrier();
    }
    __syncthreads();

    const int mt = w & 1, nh = w >> 1;
    const int m_ = mt * 16 + bb;
    f32x4 acc[4];
#pragma unroll
    for (int t = 0; t < 4; t++) acc[t] = (f32x4){0.f, 0.f, 0.f, 0.f};
    {
        const short* ar_ = hb + (size_t)s_r[m_] * 128 + quad * 8;
        const short* ac_ = hb + (size_t)s_c[m_] * 128 + quad * 8;
        gemm_grow(ar_, wb, 256, 128, nh * 4, 4, acc);
        gemm_grow(ac_, wb + 128, 256, 128, nh * 4, 4, acc);
        gemm_lds(R1, 264, wb + 32768, 256, 256, mt, nh * 4, 4, acc);
    }
    __syncthreads();
    short* V1 = R1;
    short* V2 = R1 + 4352;
    short* C1O = R1 + 8704;
#pragma unroll
    for (int t = 0; t < 4; t++)
#pragma unroll
        for (int i = 0; i < 4; i++) {
            int m = mt * 16 + quad * 4 + i, n = (nh * 4 + t) * 16 + bb;
            V1[m * 136 + n] = F2B(siluf(acc[t][i] + e1B[n] + bc[n] * s_inv[m]));
        }
    __syncthreads();

#pragma unroll
    for (int t = 0; t < 4; t++) acc[t] = (f32x4){0.f, 0.f, 0.f, 0.f};
    gemm_lds(V1, 136, wb + 65536, 128, 128, mt, nh * 4, 4, acc);
    __syncthreads();
#pragma unroll
    for (int t = 0; t < 4; t++)
#pragma unroll
        for (int i = 0; i < 4; i++) {
            int m = mt * 16 + quad * 4 + i, n = (nh * 4 + t) * 16 + bb;
            V2[m * 136 + n] = F2B(siluf(acc[t][i] + e2B[n]));
        }
    __syncthreads();

    {
        int e = tid >> 3, j = tid & 7;
        float s = 0.f;
        for (int f = j * 16; f < j * 16 + 16; f++) s += B2F(V2[e * 136 + f]) * aW[f];
        s_red8[e][j] = s;
    }
    __syncthreads();
    if (tid < 32) {
        float s = 0.f;
#pragma unroll
        for (int j = 0; j < 8; j++) s += s_red8[tid][j];
        s_gate[tid] = 1.f / (1.f + __expf(-(s + aB[0])));
    }
    __syncthreads();
    for (int p = tid; p < 32 * 128; p += 256) {
        int e = p >> 7, f = p & 127;
        V1[e * 136 + f] = F2B(B2F(V2[e * 136 + f]) * s_gate[e]);
    }
    __syncthreads();

#pragma unroll
    for (int t = 0; t < 4; t++) acc[t] = (f32x4){0.f, 0.f, 0.f, 0.f};
    gemm_lds(V1, 136, wb + 81920, 128, 128, mt, nh * 4, 4, acc);
    __syncthreads();
#pragma unroll
    for (int t = 0; t < 4; t++)
#pragma unroll
        for (int i = 0; i < 4; i++) {
            int m = mt * 16 + quad * 4 + i, n = (nh * 4 + t) * 16 + bb;
            C1O[m * 136 + n] = F2B(siluf(acc[t][i] + c1B[n]));
        }
    __syncthreads();

    if (nh == 0) {
        f32x4 a4 = (f32x4){0.f, 0.f, 0.f, 0.f};
        gemm_lds(C1O, 136, wb + 98304, 128, 128, mt, 0, 1, &a4);
#pragma unroll
        for (int i = 0; i < 4; i++) {
            int m = mt * 16 + quad * 4 + i;
            if (bb < 14) s_ch[m][bb] = a4[i] + c2B[bb];
        }
    }
    __syncthreads();

    if (tid < 32) {
        int t = (int)(csum[s_r[tid]] + 0.5f) - 1;
        if (t < 0) t = 0; if (t > 13) t = 13;
        int Wd = 14 - t;
        for (int i = 0; i < 14; i++) {
            int jend = i + Wd - 1; if (jend > 13) jend = 13;
            float a = 0.f;
            for (int j = i; j <= jend; j++) a += s_ch[tid][j];
            s_pool[tid][i] = a / (float)Wd;
        }
    }
    __syncthreads();

    for (int p = tid; p < 32 * 42; p += 256) {
        int e = p / 42, q = p - e * 42, i = q / 3, d = q - i * 3;
        float diff = s_xr2[e * 42 + q] - poolc[s_c[e] * 3 + d];
        atomicAdd(&xacc[(size_t)s_r[e] * 42 + q], diff * s_pool[e][i]);
    }
    for (int p = tid; p < 32 * 128; p += 256) {
        int e = p >> 7, f = p & 127;
        atomicAdd(&agg[(size_t)s_c[e] * 128 + f], B2F(V1[e * 136 + f]));
    }
    if (tid < 32) {
        atomicAdd(&cntr[s_r[tid]], 1.f);
        atomicAdd(&cntc[s_c[tid]], 1.f);
    }
}

// ---------------- batched node post ------------------------------------------
__global__ __launch_bounds__(256, 2) void k_node_post(
    fp h, fp x, const short* __restrict__ wb,
    fp n1B, fp n2B, fp lng, fp lnb,
    const float* __restrict__ agg, const float* __restrict__ cntc,
    const float* __restrict__ xacc, const float* __restrict__ cntr,
    float* __restrict__ outh, float* __restrict__ outx) {
    __shared__ __attribute__((aligned(16))) short nA[32 * 264];
    __shared__ __attribute__((aligned(16))) short nMid[32 * 136];
    __shared__ float nY[32][128];
    __shared__ float nred8[32][8];
    __shared__ float nmu[32], nrs[32];

    const int tid = threadIdx.x;
    const int wave = tid >> 6, mt = wave & 1, nh = wave >> 1;
    const int lane = tid & 63, bb = lane & 15, quad = lane >> 4;
    const int nb0 = blockIdx.x * 32;
    const short* n1Wb = wb + 100352;
    const short* n2Wb = wb + 133120;

    for (int p = tid; p < 32 * 128; p += 256) {
        int i = p >> 7, f = p & 127;
        int n = nb0 + i;
        nA[i * 264 + f] = F2B(h[(size_t)n * 128 + f]);
        float cc = cntc[n]; if (cc < 1.f) cc = 1.f;
        nA[i * 264 + 128 + f] = F2B(agg[(size_t)n * 128 + f] / cc);
    }
    __syncthreads();

    f32x4 acc[4];
#pragma unroll
    for (int t = 0; t < 4; t++) acc[t] = (f32x4){0.f, 0.f, 0.f, 0.f};
    gemm_lds(nA, 264, n1Wb, 256, 256, mt, nh * 4, 4, acc);
#pragma unroll
    for (int t = 0; t < 4; t++)
#pragma unroll
        for (int i = 0; i < 4; i++) {
            int m = mt * 16 + quad * 4 + i, n = (nh * 4 + t) * 16 + bb;
            nMid[m * 136 + n] = F2B(siluf(acc[t][i] + n1B[n]));
        }
    __syncthreads();

#pragma unroll
    for (int t = 0; t < 4; t++) acc[t] = (f32x4){0.f, 0.f, 0.f, 0.f};
    gemm_lds(nMid, 136, n2Wb, 128, 128, mt, nh * 4, 4, acc);
#pragma unroll
    for (int t = 0; t < 4; t++)
#pragma unroll
        for (int i = 0; i < 4; i++) {
            int m = mt * 16 + quad * 4 + i, n = (nh * 4 + t) * 16 + bb;
            nY[m][n] = acc[t][i] + n2B[n] + h[(size_t)(nb0 + m) * 128 + n];
        }
    __syncthreads();

    {
        int i = tid >> 3, j = tid & 7;
        float s = 0.f;
        for (int f = j * 16; f < j * 16 + 16; f++) s += nY[i][f];
        nred8[i][j] = s;
    }
    __syncthreads();
    if (tid < 32) {
        float s = 0.f;
#pragma unroll
        for (int j = 0; j < 8; j++) s += nred8[tid][j];
        nmu[tid] = s * (1.f / 128.f);
    }
    __syncthreads();
    {
        int i = tid >> 3, j = tid & 7;
        float mu = nmu[i], s = 0.f;
        for (int f = j * 16; f < j * 16 + 16; f++) { float d = nY[i][f] - mu; s += d * d; }
        nred8[i][j] = s;
    }
    __syncthreads();
    if (tid < 32) {
        float s = 0.f;
#pragma unroll
        for (int j = 0; j < 8; j++) s += nred8[tid][j];
        nrs[tid] = rsqrtf(s * (1.f / 128.f) + 1e-5f);
    }
    __syncthreads();
    for (int p = tid; p < 32 * 128; p += 256) {
        int i = p >> 7, f = p & 127;
        outh[(size_t)(nb0 + i) * 128 + f] = (nY[i][f] - nmu[i]) * nrs[i] * lng[f] + lnb[f];
    }
    for (int p = tid; p < 32 * 42; p += 256) {
        int i = p / 42, q = p - i * 42;
        int n = nb0 + i;
        float cr = cntr[n]; if (cr < 1.f) cr = 1.f;
        outx[(size_t)n * 42 + q] = x[(size_t)n * 42 + q] + xacc[(size_t)n * 42 + q] / cr;
    }
}

extern "C" void kernel_launch(void* const* d_in, const int* in_sizes, int n_in,
                              void* d_out, int out_size, void* d_ws, size_t ws_size,
                              hipStream_t stream) {
    fp h   = (fp)d_in[0];
    fp x   = (fp)d_in[1];
    const int* row = (const int*)d_in[2];
    const int* col = (const int*)d_in[3];
    fp attr= (fp)d_in[4];
    fp cw  = (fp)d_in[5];
    fp rW  = (fp)d_in[6];  fp rB  = (fp)d_in[7];
    fp e1W = (fp)d_in[8];  fp e1B = (fp)d_in[9];
    fp e2W = (fp)d_in[10]; fp e2B = (fp)d_in[11];
    fp aW  = (fp)d_in[12]; fp aB  = (fp)d_in[13];
    fp c1W = (fp)d_in[14]; fp c1B = (fp)d_in[15];
    fp c2W = (fp)d_in[16]; fp c2B = (fp)d_in[17];
    fp n1W = (fp)d_in[18]; fp n1B = (fp)d_in[19];
    fp n2W = (fp)d_in[20]; fp n2B = (fp)d_in[21];
    fp lng = (fp)d_in[22]; fp lnb = (fp)d_in[23];

    // fp32-offset layout:
    // xacc 0 | agg 840000 | cntr 3400000 | cntc 3420000 | csum 3440000
    // pool 3460000 | bc 3520000 | hb 3520128 (1.28M f32 eq) | wb 4800128 (74752)
    // H12 4874880 (2.56M f32 eq) | e1p 7434880 (20.48M f32 eq) | end 27914880
    float* ws   = (float*)d_ws;
    float* xacc = ws;
    float* agg  = ws + 840000;
    float* cntr = ws + 3400000;
    float* cntc = ws + 3420000;
    float* csum = ws + 3440000;
    float* pool = ws + 3460000;
    float* bc   = ws + 3520000;
    short* hb   = (short*)(ws + 3520128);
    short* wb   = (short*)(ws + 4800128);
    short* H12  = (short*)(ws + 4874880);
    short* e1p  = (short*)(ws + 7434880);

    const size_t need = 27914880ull * 4ull;

    hipMemsetAsync(d_ws, 0, 3440000 * sizeof(float), stream);

    k_prep_w<<<(149504 + 255) / 256, 256, 0, stream>>>(e1W, e2W, c1W, c2W, n1W, n2W, wb);
    k_fold<<<128, 256, 0, stream>>>(e1W, rW, rB, wb, bc);
    k_prep_h<<<(NN * 128 + 255) / 256, 256, 0, stream>>>(h, hb);
    k_node_pre<<<(NN + 255) / 256, 256, 0, stream>>>(x, cw, csum, pool);

    if (ws_size >= need) {
        k_hw<<<NN / 32, 256, 0, stream>>>(hb, wb, H12);
        k_radial<<<NE / 64, 256, 0, stream>>>(x, row, col, attr, cw, wb, bc, e1p);
        k_edge_split<<<NE / 32, 256, 0, stream>>>(x, row, col, H12, e1p, wb,
                                                  e1B, e2B, aW, aB, c1B, c2B,
                                                  csum, pool, xacc, agg, cntr, cntc);
    } else {
        k_edge_fused<<<NE / 32, 256, 0, stream>>>(x, row, col, attr, cw, hb, wb,
                                                  e1B, e2B, aW, aB, c1B, c2B,
                                                  bc, csum, pool, xacc, agg, cntr, cntc);
    }

    float* outh = (float*)d_out;
    float* outx = outh + NN * 128;
    k_node_post<<<NN / 32, 256, 0, stream>>>(h, x, wb, n1B, n2B, lng, lnb,
                                             agg, cntc, xacc, cntr, outh, outx);
}

// Round 8
// 879.776 us; speedup vs baseline: 1.4833x; 1.3315x over previous
//
#include <hip/hip_runtime.h>
#include <math.h>

#define NN 20000
#define NE 320000

typedef const float* fp;
typedef short short8 __attribute__((ext_vector_type(8)));
typedef float f32x4 __attribute__((ext_vector_type(4)));

__device__ __forceinline__ short F2B(float f) {           // exact RNE (prep only)
    unsigned u = __float_as_uint(f);
    return (short)((u + 0x7fffu + ((u >> 16) & 1u)) >> 16);
}
__device__ __forceinline__ short F2Bf(float f) {          // fast round (hot path)
    return (short)((__float_as_uint(f) + 0x8000u) >> 16);
}
__device__ __forceinline__ float B2F(short s) {
    return __uint_as_float(((unsigned)(unsigned short)s) << 16);
}
__device__ __forceinline__ float siluf(float v) { return v / (1.f + __expf(-v)); }

// ---------------- weight fp32->bf16 (layout in shorts): ---------------------
// 0: e1hh[128][256] | 32768: Wc[128][256] (k_fold) | 65536: e2W | 81920: c1W
// 98304: c2W[16][128] | 100352: n1W[128][256] | 133120: n2W  end 149504
__global__ void k_prep_w(fp e1W, fp e2W, fp c1W, fp c2W, fp n1W, fp n2W,
                         short* __restrict__ wb) {
    int i = blockIdx.x * 256 + threadIdx.x;
    if (i >= 149504) return;
    if (i >= 32768 && i < 65536) return;
    float v;
    if (i < 32768)       { int o = i >> 8, k = i & 255; v = e1W[o * 384 + k]; }
    else if (i < 81920)  v = e2W[i - 65536];
    else if (i < 98304)  v = c1W[i - 81920];
    else if (i < 100352) { int q = i - 98304; v = (q < 1792) ? c2W[q] : 0.f; }
    else if (i < 133120) v = n1W[i - 100352];
    else                 v = n2W[i - 133120];
    wb[i] = F2B(v);
}

__global__ void k_fold(fp e1W, fp rW, fp rB, short* __restrict__ wb,
                       float* __restrict__ bc) {
    int o = blockIdx.x, k = threadIdx.x;
    float acc = 0.f;
    for (int m = 0; m < 128; m++) acc += e1W[o * 384 + 256 + m] * rW[m * 256 + k];
    wb[32768 + o * 256 + k] = F2B(acc);
    if (k == 0) {
        float b = 0.f;
        for (int m = 0; m < 128; m++) b += e1W[o * 384 + 256 + m] * rB[m];
        bc[o] = b;
    }
}

__global__ void k_prep_h(fp h, short* __restrict__ hb) {
    int i = blockIdx.x * 256 + threadIdx.x;
    if (i < NN * 128) hb[i] = F2B(h[i]);
}

// attrT[n][a(16)][c(16)] = attr[n][c][a], c>=14 zero -> both MFMA fragments
// become single short8 loads.
__global__ void k_prep_attrT(fp attr, short* __restrict__ aT) {
    int i = blockIdx.x * 256 + threadIdx.x;   // n*256 + c*16 + a (a fast: coalesced reads)
    if (i >= NN * 256) return;
    int n = i >> 8, rem = i & 255, c = rem >> 4, a = rem & 15;
    float v = (c < 14) ? attr[(size_t)n * 224 + c * 16 + a] : 0.f;
    aT[(size_t)n * 256 + a * 16 + c] = F2B(v);
}

__global__ void k_node_pre(fp x, fp cw, float* __restrict__ csum, float* __restrict__ pool) {
    int n = blockIdx.x * blockDim.x + threadIdx.x;
    if (n >= NN) return;
    float cnt = 0.f, px = 0.f, py = 0.f, pz = 0.f;
#pragma unroll
    for (int c = 0; c < 14; c++) {
        float w = cw[n * 14 + c];
        if (w != 0.f) {
            cnt += 1.f;
            px += x[(n * 14 + c) * 3 + 0];
            py += x[(n * 14 + c) * 3 + 1];
            pz += x[(n * 14 + c) * 3 + 2];
        }
    }
    if (cnt < 1.f) cnt = 1.f;
    csum[n] = cnt;
    pool[n * 3 + 0] = px / cnt;
    pool[n * 3 + 1] = py / cnt;
    pool[n * 3 + 2] = pz / cnt;
}

__device__ __forceinline__ void gemm_lds(const short* __restrict__ A, int sA,
                                         const short* __restrict__ W, int Ws, int K,
                                         int mt, int nt0, int nts, f32x4* acc) {
    const int lane = threadIdx.x & 63;
    const short* ap = A + (mt * 16 + (lane & 15)) * sA + ((lane >> 4) * 8);
    for (int k0 = 0; k0 < K; k0 += 32) {
        short8 a = *(const short8*)(ap + k0);
#pragma unroll
        for (int t = 0; t < nts; t++) {
            short8 b = *(const short8*)(W + ((nt0 + t) * 16 + (lane & 15)) * Ws + k0 + ((lane >> 4) * 8));
            acc[t] = __builtin_amdgcn_mfma_f32_16x16x32_bf16(a, b, acc[t], 0, 0, 0);
        }
    }
}
__device__ __forceinline__ void gemm_grow(const short* __restrict__ arow,
                                          const short* __restrict__ W, int Ws, int K,
                                          int nt0, int nts, f32x4* acc) {
    const int lane = threadIdx.x & 63;
    for (int k0 = 0; k0 < K; k0 += 32) {
        short8 a = *(const short8*)(arow + k0);
#pragma unroll
        for (int t = 0; t < nts; t++) {
            short8 b = *(const short8*)(W + ((nt0 + t) * 16 + (lane & 15)) * Ws + k0 + ((lane >> 4) * 8));
            acc[t] = __builtin_amdgcn_mfma_f32_16x16x32_bf16(a, b, acc[t], 0, 0, 0);
        }
    }
}

// ---------------- H12: per-node h@W1 | h@W2 (bf16 out) -----------------------
__global__ __launch_bounds__(256, 2) void k_hw(const short* __restrict__ hb,
                                               const short* __restrict__ wb,
                                               short* __restrict__ H12) {
    __shared__ __attribute__((aligned(16))) short A[32 * 136];
    const int tid = threadIdx.x, lane = tid & 63, w = tid >> 6;
    const int bb = lane & 15, quad = lane >> 4;
    const int mt = w & 1, nh = w >> 1, nb0 = blockIdx.x * 32;
    for (int p = tid; p < 512; p += 256) {
        int i = p >> 4, v = p & 15;
        *(short8*)(A + i * 136 + v * 8) = *(const short8*)(hb + (size_t)(nb0 + i) * 128 + v * 8);
    }
    __syncthreads();
    f32x4 acc[4];
#pragma unroll
    for (int t = 0; t < 4; t++) acc[t] = (f32x4){0.f, 0.f, 0.f, 0.f};
    gemm_lds(A, 136, wb, 256, 128, mt, nh * 4, 4, acc);
#pragma unroll
    for (int t = 0; t < 4; t++)
#pragma unroll
        for (int i = 0; i < 4; i++) {
            int m = mt * 16 + quad * 4 + i, n = (nh * 4 + t) * 16 + bb;
            H12[(size_t)(nb0 + m) * 256 + n] = F2Bf(acc[t][i]);
        }
#pragma unroll
    for (int t = 0; t < 4; t++) acc[t] = (f32x4){0.f, 0.f, 0.f, 0.f};
    gemm_lds(A, 136, wb + 128, 256, 128, mt, nh * 4, 4, acc);
#pragma unroll
    for (int t = 0; t < 4; t++)
#pragma unroll
        for (int i = 0; i < 4; i++) {
            int m = mt * 16 + quad * 4 + i, n = (nh * 4 + t) * 16 + bb;
            H12[(size_t)(nb0 + m) * 256 + 128 + n] = F2Bf(acc[t][i]);
        }
}

// ---------------- radial: wave=16 edges, bf16 attrT fragment loads -----------
__global__ __launch_bounds__(256, 4) void k_radial(
    fp x, const int* __restrict__ row, const int* __restrict__ col,
    const short* __restrict__ attrT, fp cw,
    const short* __restrict__ wb, const float* __restrict__ bc,
    short* __restrict__ e1p) {
    __shared__ __attribute__((aligned(16))) short Arad[4][16 * 264];
    __shared__ float xc2[4][2][48];
    __shared__ float cwc2[4][2][16];
    __shared__ float inv16[4][16];
    const int tid = threadIdx.x, lane = tid & 63, w = tid >> 6;
    const int bb = lane & 15, quad = lane >> 4;
    const int e0 = blockIdx.x * 64 + w * 16;
    const short* Wc = wb + 32768;
    short* Ar = Arad[w];

#pragma unroll 2
    for (int m = 0; m < 16; m++) {
        const int e = e0 + m;
        const int r = row[e], c = col[e];
        const int bufi = m & 1;
        // fragment loads first (single short8 each; c=14,15 pre-zeroed in attrT)
        short8 arv = (short8){0, 0, 0, 0, 0, 0, 0, 0};
        short8 acv = (short8){0, 0, 0, 0, 0, 0, 0, 0};
        if (quad < 2) {
            arv = *(const short8*)(attrT + (size_t)r * 256 + bb * 16 + quad * 8);
            acv = *(const short8*)(attrT + (size_t)c * 256 + bb * 16 + quad * 8);
        }
        if (lane < 42)      xc2[w][bufi][lane] = x[(size_t)c * 42 + lane];
        else if (lane < 56) cwc2[w][bufi][lane - 42] = cw[c * 14 + (lane - 42)];
        const int iic = bb < 14 ? bb : 13;
        float xr0 = x[(size_t)r * 42 + iic * 3];
        float xr1 = x[(size_t)r * 42 + iic * 3 + 1];
        float xr2 = x[(size_t)r * 42 + iic * 3 + 2];
        float cwr = cw[r * 14 + iic];
        short8 msgv = (short8){0, 0, 0, 0, 0, 0, 0, 0};
        if (quad < 2) {
#pragma unroll
            for (int t = 0; t < 8; t++) {
                int jj = quad * 8 + t, jc = jj < 14 ? jj : 13;
                float dx = xr0 - xc2[w][bufi][jc * 3];
                float dy = xr1 - xc2[w][bufi][jc * 3 + 1];
                float dz = xr2 - xc2[w][bufi][jc * 3 + 2];
                float mm = sqrtf(dx * dx + dy * dy + dz * dz) * cwr * cwc2[w][bufi][jc];
                msgv[t] = (bb < 14 && jj < 14) ? F2Bf(mm) : (short)0;
            }
        }
        // MFMA1: t2 = msg @ ac
        f32x4 t2 = (f32x4){0.f, 0.f, 0.f, 0.f};
        t2 = __builtin_amdgcn_mfma_f32_16x16x32_bf16(msgv, acv, t2, 0, 0, 0);
        // redistribute t2 (C-layout) -> B-fragment via shuffles
        short8 t2v;
#pragma unroll
        for (int t = 0; t < 8; t++) {
            int grp = (2 * quad + (t >> 2)) & 3;
            float v = __shfl(t2[t & 3], bb + 16 * grp, 64);
            t2v[t] = (quad < 2) ? F2Bf(v) : (short)0;
        }
        // MFMA2: rad = ar^T @ t2
        f32x4 rad = (f32x4){0.f, 0.f, 0.f, 0.f};
        rad = __builtin_amdgcn_mfma_f32_16x16x32_bf16(arv, t2v, rad, 0, 0, 0);
        float ss = rad[0] * rad[0] + rad[1] * rad[1] + rad[2] * rad[2] + rad[3] * rad[3];
#pragma unroll
        for (int off = 32; off > 0; off >>= 1) ss += __shfl_xor(ss, off, 64);
        float inv = 1.f / (sqrtf(ss) + 1.f);
        if (lane == 0) inv16[w][m] = inv;
#pragma unroll
        for (int g = 0; g < 4; g++)
            Ar[m * 264 + (quad * 4 + g) * 16 + bb] = F2Bf(rad[g] * inv);
    }
    __builtin_amdgcn_wave_barrier();

    // GEMM: [16x256] @ Wc^T -> [16x128]
    f32x4 acc[8];
#pragma unroll
    for (int t = 0; t < 8; t++) acc[t] = (f32x4){0.f, 0.f, 0.f, 0.f};
    for (int k0 = 0; k0 < 256; k0 += 32) {
        short8 a = *(const short8*)(Ar + bb * 264 + k0 + quad * 8);
#pragma unroll
        for (int t = 0; t < 8; t++) {
            short8 b = *(const short8*)(Wc + (t * 16 + bb) * 256 + k0 + quad * 8);
            acc[t] = __builtin_amdgcn_mfma_f32_16x16x32_bf16(a, b, acc[t], 0, 0, 0);
        }
    }
    short* E1 = Ar;
#pragma unroll
    for (int t = 0; t < 8; t++)
#pragma unroll
        for (int i = 0; i < 4; i++) {
            int m = quad * 4 + i, n = t * 16 + bb;
            E1[m * 136 + n] = F2Bf(acc[t][i] + inv16[w][m] * bc[n]);
        }
    __builtin_amdgcn_wave_barrier();
    for (int p = lane; p < 256; p += 64) {
        int m = p >> 4, v = p & 15;
        *(short8*)(e1p + (size_t)(e0 + m) * 128 + v * 8) = *(const short8*)(E1 + m * 136 + v * 8);
    }
}

// ---------------- slim fused edge kernel (split path) ------------------------
__global__ __launch_bounds__(256, 6) void k_edge_split(
    fp x, const int* __restrict__ row, const int* __restrict__ col,
    const short* __restrict__ H12, const short* __restrict__ e1p,
    const short* __restrict__ wb,
    fp e1B, fp e2B, fp aW, fp aB, fp c1B, fp c2B,
    const float* __restrict__ csum, const float* __restrict__ poolc,
    float* __restrict__ xacc, float* __restrict__ agg,
    float* __restrict__ cntr, float* __restrict__ cntc) {
    __shared__ __attribute__((aligned(16))) short V1[32 * 136];
    __shared__ __attribute__((aligned(16))) short V2[32 * 136];
    __shared__ int s_r[32], s_c[32];
    __shared__ float s_ch[32][14], s_pool[32][14];
    __shared__ float s_red8[32][8], s_gate[32];

    const int tid = threadIdx.x, lane = tid & 63, w = tid >> 6;
    const int bb = lane & 15, quad = lane >> 4;
    const int mt = w & 1, nh = w >> 1;
    const int e0 = blockIdx.x * 32;

    if (tid < 32) { s_r[tid] = row[e0 + tid]; s_c[tid] = col[e0 + tid]; }
    __syncthreads();

    for (int p = tid; p < 512; p += 256) {
        int e = p >> 4, v = p & 15;
        short8 hr = *(const short8*)(H12 + (size_t)s_r[e] * 256 + v * 8);
        short8 hc = *(const short8*)(H12 + (size_t)s_c[e] * 256 + 128 + v * 8);
        short8 pp = *(const short8*)(e1p + (size_t)(e0 + e) * 128 + v * 8);
        short8 o;
#pragma unroll
        for (int j = 0; j < 8; j++)
            o[j] = F2Bf(siluf(B2F(hr[j]) + B2F(hc[j]) + B2F(pp[j]) + e1B[v * 8 + j]));
        *(short8*)(V1 + e * 136 + v * 8) = o;
    }
    __syncthreads();

    f32x4 acc[4];
#pragma unroll
    for (int t = 0; t < 4; t++) acc[t] = (f32x4){0.f, 0.f, 0.f, 0.f};
    gemm_lds(V1, 136, wb + 65536, 128, 128, mt, nh * 4, 4, acc);
#pragma unroll
    for (int t = 0; t < 4; t++)
#pragma unroll
        for (int i = 0; i < 4; i++) {
            int m = mt * 16 + quad * 4 + i, n = (nh * 4 + t) * 16 + bb;
            V2[m * 136 + n] = F2Bf(siluf(acc[t][i] + e2B[n]));
        }
    __syncthreads();

    {
        int e = tid >> 3, j = tid & 7;
        float s = 0.f;
        for (int f = j * 16; f < j * 16 + 16; f++) s += B2F(V2[e * 136 + f]) * aW[f];
        s_red8[e][j] = s;
    }
    __syncthreads();
    if (tid < 32) {
        float s = 0.f;
#pragma unroll
        for (int j = 0; j < 8; j++) s += s_red8[tid][j];
        s_gate[tid] = 1.f / (1.f + __expf(-(s + aB[0])));
    }
    __syncthreads();
    for (int p = tid; p < 32 * 128; p += 256) {
        int e = p >> 7, f = p & 127;
        V1[e * 136 + f] = F2Bf(B2F(V2[e * 136 + f]) * s_gate[e]);
    }
    __syncthreads();

#pragma unroll
    for (int t = 0; t < 4; t++) acc[t] = (f32x4){0.f, 0.f, 0.f, 0.f};
    gemm_lds(V1, 136, wb + 81920, 128, 128, mt, nh * 4, 4, acc);
    __syncthreads();
#pragma unroll
    for (int t = 0; t < 4; t++)
#pragma unroll
        for (int i = 0; i < 4; i++) {
            int m = mt * 16 + quad * 4 + i, n = (nh * 4 + t) * 16 + bb;
            V2[m * 136 + n] = F2Bf(siluf(acc[t][i] + c1B[n]));
        }
    __syncthreads();

    if (nh == 0) {
        f32x4 a4 = (f32x4){0.f, 0.f, 0.f, 0.f};
        gemm_lds(V2, 136, wb + 98304, 128, 128, mt, 0, 1, &a4);
#pragma unroll
        for (int i = 0; i < 4; i++) {
            int m = mt * 16 + quad * 4 + i;
            if (bb < 14) s_ch[m][bb] = a4[i] + c2B[bb];
        }
    }
    __syncthreads();

    if (tid < 32) {
        int t = (int)(csum[s_r[tid]] + 0.5f) - 1;
        if (t < 0) t = 0; if (t > 13) t = 13;
        int Wd = 14 - t;
        for (int i = 0; i < 14; i++) {
            int jend = i + Wd - 1; if (jend > 13) jend = 13;
            float a = 0.f;
            for (int j = i; j <= jend; j++) a += s_ch[tid][j];
            s_pool[tid][i] = a / (float)Wd;
        }
    }
    __syncthreads();

    for (int p = tid; p < 32 * 42; p += 256) {
        int e = p / 42, q = p - e * 42, i = q / 3, d = q - i * 3;
        float diff = x[(size_t)s_r[e] * 42 + q] - poolc[s_c[e] * 3 + d];
        atomicAdd(&xacc[(size_t)s_r[e] * 42 + q], diff * s_pool[e][i]);
    }
    for (int p = tid; p < 32 * 128; p += 256) {
        int e = p >> 7, f = p & 127;
        atomicAdd(&agg[(size_t)s_c[e] * 128 + f], B2F(V1[e * 136 + f]));
    }
    if (tid < 32) {
        atomicAdd(&cntr[s_r[tid]], 1.f);
        atomicAdd(&cntc[s_c[tid]], 1.f);
    }
}

// ---------------- fused fallback (round-5 kernel, unchanged) -----------------
__global__ __launch_bounds__(256, 3) void k_edge_fused(
    fp x, const int* __restrict__ row, const int* __restrict__ col,
    fp attr, fp cw, const short* __restrict__ hb, const short* __restrict__ wb,
    fp e1B, fp e2B, fp aW, fp aB, fp c1B, fp c2B,
    const float* __restrict__ bc, const float* __restrict__ csum,
    const float* __restrict__ poolc,
    float* __restrict__ xacc, float* __restrict__ agg,
    float* __restrict__ cntr, float* __restrict__ cntc) {
    __shared__ __attribute__((aligned(16))) short R1[13056];
    __shared__ float s_xr2[32 * 42];
    __shared__ float T[4][352];
    __shared__ int   s_r[32], s_c[32];
    __shared__ float s_inv[32];
    __shared__ float s_ch[32][14], s_pool[32][14];
    __shared__ float s_red8[32][8];
    __shared__ float s_gate[32];

    const int tid = threadIdx.x, lane = tid & 63, w = tid >> 6;
    const int bb = lane & 15, quad = lane >> 4;

    if (tid < 32) { s_r[tid] = row[blockIdx.x * 32 + tid]; s_c[tid] = col[blockIdx.x * 32 + tid]; }
    __syncthreads();

    float* slot = T[w];
    float* t2w = slot + 72;
    for (int i8 = 0; i8 < 8; i8++) {
        const int e = w * 8 + i8;
        const int r = s_r[e], cl = s_c[e];
        if (lane < 42) {
            s_xr2[e * 42 + lane] = x[(size_t)r * 42 + lane];
            slot[lane] = x[(size_t)cl * 42 + lane];
        }
        if (lane < 14)      slot[42 + lane] = cw[r * 14 + lane];
        else if (lane < 28) slot[56 + (lane - 14)] = cw[cl * 14 + (lane - 14)];
        __builtin_amdgcn_wave_barrier();

        const int iic = bb < 14 ? bb : 13;
        float xr0 = s_xr2[e * 42 + iic * 3], xr1 = s_xr2[e * 42 + iic * 3 + 1],
              xr2v = s_xr2[e * 42 + iic * 3 + 2];
        float cwri = slot[42 + iic];
        short8 msgv, acv;
#pragma unroll
        for (int t = 0; t < 8; t++) {
            int jj = quad * 8 + t, jc = jj < 14 ? jj : 13;
            float dx = xr0 - slot[jc * 3], dy = xr1 - slot[jc * 3 + 1], dz = xr2v - slot[jc * 3 + 2];
            float m = sqrtf(dx * dx + dy * dy + dz * dz) * cwri * slot[56 + jc];
            msgv[t] = (bb < 14 && jj < 14) ? F2B(m) : (short)0;
            acv[t] = F2B(attr[(size_t)cl * 224 + jc * 16 + bb]);
        }
        f32x4 t2 = (f32x4){0.f, 0.f, 0.f, 0.f};
        t2 = __builtin_amdgcn_mfma_f32_16x16x32_bf16(msgv, acv, t2, 0, 0, 0);
#pragma unroll
        for (int g = 0; g < 4; g++) t2w[(quad * 4 + g) * 17 + bb] = t2[g];
        __builtin_amdgcn_wave_barrier();

        short8 arv, t2v;
#pragma unroll
        for (int t = 0; t < 8; t++) {
            int kk = quad * 8 + t, kc = kk < 16 ? kk : 15;
            t2v[t] = F2B(t2w[kc * 17 + bb]);
            arv[t] = (kk < 14) ? F2B(attr[(size_t)r * 224 + kk * 16 + bb]) : (short)0;
        }
        f32x4 rad = (f32x4){0.f, 0.f, 0.f, 0.f};
        rad = __builtin_amdgcn_mfma_f32_16x16x32_bf16(arv, t2v, rad, 0, 0, 0);

        float ss = rad[0] * rad[0] + rad[1] * rad[1] + rad[2] * rad[2] + rad[3] * rad[3];
#pragma unroll
        for (int off = 32; off > 0; off >>= 1) ss += __shfl_xor(ss, off, 64);
        float inv = 1.f / (sqrtf(ss) + 1.f);
        if (lane == 0) s_inv[e] = inv;
#pragma unroll
        for (int g = 0; g < 4; g++)
            R1[e * 264 + (quad * 4 + g) * 16 + bb] = F2B(rad[g] * inv);
        __builtin_amdgcn_wave_barrier();
    }
    __syncthreads();

    const int mt = w & 1, nh = w >> 1;
    const int m_ = mt * 16 + bb;
    f32x4 acc[4];
#pragma unroll
    for (int t = 0; t < 4; t++) acc[t] = (f32x4){0.f, 0.f, 0.f, 0.f};
    {
        const short* ar_ = hb + (size_t)s_r[m_] * 128 + quad * 8;
        const short* ac_ = hb + (size_t)s_c[m_] * 128 + quad * 8;
        gemm_grow(ar_, wb, 256, 128, nh * 4, 4, acc);
        gemm_grow(ac_, wb + 128, 256, 128, nh * 4, 4, acc);
        gemm_lds(R1, 264, wb + 32768, 256, 256, mt, nh * 4, 4, acc);
    }
    __syncthreads();
    short* V1 = R1;
    short* V2 = R1 + 4352;
    short* C1O = R1 + 8704;
#pragma unroll
    for (int t = 0; t < 4; t++)
#pragma unroll
        for (int i = 0; i < 4; i++) {
            int m = mt * 16 + quad * 4 + i, n = (nh * 4 + t) * 16 + bb;
            V1[m * 136 + n] = F2B(siluf(acc[t][i] + e1B[n] + bc[n] * s_inv[m]));
        }
    __syncthreads();

#pragma unroll
    for (int t = 0; t < 4; t++) acc[t] = (f32x4){0.f, 0.f, 0.f, 0.f};
    gemm_lds(V1, 136, wb + 65536, 128, 128, mt, nh * 4, 4, acc);
    __syncthreads();
#pragma unroll
    for (int t = 0; t < 4; t++)
#pragma unroll
        for (int i = 0; i < 4; i++) {
            int m = mt * 16 + quad * 4 + i, n = (nh * 4 + t) * 16 + bb;
            V2[m * 136 + n] = F2B(siluf(acc[t][i] + e2B[n]));
        }
    __syncthreads();

    {
        int e = tid >> 3, j = tid & 7;
        float s = 0.f;
        for (int f = j * 16; f < j * 16 + 16; f++) s += B2F(V2[e * 136 + f]) * aW[f];
        s_red8[e][j] = s;
    }
    __syncthreads();
    if (tid < 32) {
        float s = 0.f;
#pragma unroll
        for (int j = 0; j < 8; j++) s += s_red8[tid][j];
        s_gate[tid] = 1.f / (1.f + __expf(-(s + aB[0])));
    }
    __syncthreads();
    for (int p = tid; p < 32 * 128; p += 256) {
        int e = p >> 7, f = p & 127;
        V1[e * 136 + f] = F2B(B2F(V2[e * 136 + f]) * s_gate[e]);
    }
    __syncthreads();

#pragma unroll
    for (int t = 0; t < 4; t++) acc[t] = (f32x4){0.f, 0.f, 0.f, 0.f};
    gemm_lds(V1, 136, wb + 81920, 128, 128, mt, nh * 4, 4, acc);
    __syncthreads();
#pragma unroll
    for (int t = 0; t < 4; t++)
#pragma unroll
        for (int i = 0; i < 4; i++) {
            int m = mt * 16 + quad * 4 + i, n = (nh * 4 + t) * 16 + bb;
            C1O[m * 136 + n] = F2B(siluf(acc[t][i] + c1B[n]));
        }
    __syncthreads();

    if (nh == 0) {
        f32x4 a4 = (f32x4){0.f, 0.f, 0.f, 0.f};
        gemm_lds(C1O, 136, wb + 98304, 128, 128, mt, 0, 1, &a4);
#pragma unroll
        for (int i = 0; i < 4; i++) {
            int m = mt * 16 + quad * 4 + i;
            if (bb < 14) s_ch[m][bb] = a4[i] + c2B[bb];
        }
    }
    __syncthreads();

    if (tid < 32) {
        int t = (int)(csum[s_r[tid]] + 0.5f) - 1;
        if (t < 0) t = 0; if (t > 13) t = 13;
        int Wd = 14 - t;
        for (int i = 0; i < 14; i++) {
            int jend = i + Wd - 1; if (jend > 13) jend = 13;
            float a = 0.f;
            for (int j = i; j <= jend; j++) a += s_ch[tid][j];
            s_pool[tid][i] = a / (float)Wd;
        }
    }
    __syncthreads();

    for (int p = tid; p < 32 * 42; p += 256) {
        int e = p / 42, q = p - e * 42, i = q / 3, d = q - i * 3;
        float diff = s_xr2[e * 42 + q] - poolc[s_c[e] * 3 + d];
        atomicAdd(&xacc[(size_t)s_r[e] * 42 + q], diff * s_pool[e][i]);
    }
    for (int p = tid; p < 32 * 128; p += 256) {
        int e = p >> 7, f = p & 127;
        atomicAdd(&agg[(size_t)s_c[e] * 128 + f], B2F(V1[e * 136 + f]));
    }
    if (tid < 32) {
        atomicAdd(&cntr[s_r[tid]], 1.f);
        atomicAdd(&cntc[s_c[tid]], 1.f);
    }
}

// ---------------- batched node post ------------------------------------------
__global__ __launch_bounds__(256, 2) void k_node_post(
    fp h, fp x, const short* __restrict__ wb,
    fp n1B, fp n2B, fp lng, fp lnb,
    const float* __restrict__ agg, const float* __restrict__ cntc,
    const float* __restrict__ xacc, const float* __restrict__ cntr,
    float* __restrict__ outh, float* __restrict__ outx) {
    __shared__ __attribute__((aligned(16))) short nA[32 * 264];
    __shared__ __attribute__((aligned(16))) short nMid[32 * 136];
    __shared__ float nY[32][128];
    __shared__ float nred8[32][8];
    __shared__ float nmu[32], nrs[32];

    const int tid = threadIdx.x;
    const int wave = tid >> 6, mt = wave & 1, nh = wave >> 1;
    const int lane = tid & 63, bb = lane & 15, quad = lane >> 4;
    const int nb0 = blockIdx.x * 32;
    const short* n1Wb = wb + 100352;
    const short* n2Wb = wb + 133120;

    for (int p = tid; p < 32 * 128; p += 256) {
        int i = p >> 7, f = p & 127;
        int n = nb0 + i;
        nA[i * 264 + f] = F2Bf(h[(size_t)n * 128 + f]);
        float cc = cntc[n]; if (cc < 1.f) cc = 1.f;
        nA[i * 264 + 128 + f] = F2Bf(agg[(size_t)n * 128 + f] / cc);
    }
    __syncthreads();

    f32x4 acc[4];
#pragma unroll
    for (int t = 0; t < 4; t++) acc[t] = (f32x4){0.f, 0.f, 0.f, 0.f};
    gemm_lds(nA, 264, n1Wb, 256, 256, mt, nh * 4, 4, acc);
#pragma unroll
    for (int t = 0; t < 4; t++)
#pragma unroll
        for (int i = 0; i < 4; i++) {
            int m = mt * 16 + quad * 4 + i, n = (nh * 4 + t) * 16 + bb;
            nMid[m * 136 + n] = F2Bf(siluf(acc[t][i] + n1B[n]));
        }
    __syncthreads();

#pragma unroll
    for (int t = 0; t < 4; t++) acc[t] = (f32x4){0.f, 0.f, 0.f, 0.f};
    gemm_lds(nMid, 136, n2Wb, 128, 128, mt, nh * 4, 4, acc);
#pragma unroll
    for (int t = 0; t < 4; t++)
#pragma unroll
        for (int i = 0; i < 4; i++) {
            int m = mt * 16 + quad * 4 + i, n = (nh * 4 + t) * 16 + bb;
            nY[m][n] = acc[t][i] + n2B[n] + h[(size_t)(nb0 + m) * 128 + n];
        }
    __syncthreads();

    {
        int i = tid >> 3, j = tid & 7;
        float s = 0.f;
        for (int f = j * 16; f < j * 16 + 16; f++) s += nY[i][f];
        nred8[i][j] = s;
    }
    __syncthreads();
    if (tid < 32) {
        float s = 0.f;
#pragma unroll
        for (int j = 0; j < 8; j++) s += nred8[tid][j];
        nmu[tid] = s * (1.f / 128.f);
    }
    __syncthreads();
    {
        int i = tid >> 3, j = tid & 7;
        float mu = nmu[i], s = 0.f;
        for (int f = j * 16; f < j * 16 + 16; f++) { float d = nY[i][f] - mu; s += d * d; }
        nred8[i][j] = s;
    }
    __syncthreads();
    if (tid < 32) {
        float s = 0.f;
#pragma unroll
        for (int j = 0; j < 8; j++) s += nred8[tid][j];
        nrs[tid] = rsqrtf(s * (1.f / 128.f) + 1e-5f);
    }
    __syncthreads();
    for (int p = tid; p < 32 * 128; p += 256) {
        int i = p >> 7, f = p & 127;
        outh[(size_t)(nb0 + i) * 128 + f] = (nY[i][f] - nmu[i]) * nrs[i] * lng[f] + lnb[f];
    }
    for (int p = tid; p < 32 * 42; p += 256) {
        int i = p / 42, q = p - i * 42;
        int n = nb0 + i;
        float cr = cntr[n]; if (cr < 1.f) cr = 1.f;
        outx[(size_t)n * 42 + q] = x[(size_t)n * 42 + q] + xacc[(size_t)n * 42 + q] / cr;
    }
}

extern "C" void kernel_launch(void* const* d_in, const int* in_sizes, int n_in,
                              void* d_out, int out_size, void* d_ws, size_t ws_size,
                              hipStream_t stream) {
    fp h   = (fp)d_in[0];
    fp x   = (fp)d_in[1];
    const int* row = (const int*)d_in[2];
    const int* col = (const int*)d_in[3];
    fp attr= (fp)d_in[4];
    fp cw  = (fp)d_in[5];
    fp rW  = (fp)d_in[6];  fp rB  = (fp)d_in[7];
    fp e1W = (fp)d_in[8];  fp e1B = (fp)d_in[9];
    fp e2W = (fp)d_in[10]; fp e2B = (fp)d_in[11];
    fp aW  = (fp)d_in[12]; fp aB  = (fp)d_in[13];
    fp c1W = (fp)d_in[14]; fp c1B = (fp)d_in[15];
    fp c2W = (fp)d_in[16]; fp c2B = (fp)d_in[17];
    fp n1W = (fp)d_in[18]; fp n1B = (fp)d_in[19];
    fp n2W = (fp)d_in[20]; fp n2B = (fp)d_in[21];
    fp lng = (fp)d_in[22]; fp lnb = (fp)d_in[23];

    // fp32-offset layout:
    // xacc 0 | agg 840000 | cntr 3400000 | cntc 3420000 | csum 3440000
    // pool 3460000 | bc 3520000 | hb 3520128 | wb 4800128 | H12 4874880
    // e1p 7434880 | attrT 27914880 | end 30474880
    float* ws    = (float*)d_ws;
    float* xacc  = ws;
    float* agg   = ws + 840000;
    float* cntr  = ws + 3400000;
    float* cntc  = ws + 3420000;
    float* csum  = ws + 3440000;
    float* pool  = ws + 3460000;
    float* bc    = ws + 3520000;
    short* hb    = (short*)(ws + 3520128);
    short* wb    = (short*)(ws + 4800128);
    short* H12   = (short*)(ws + 4874880);
    short* e1p   = (short*)(ws + 7434880);
    short* attrT = (short*)(ws + 27914880);

    const size_t need = 30474880ull * 4ull;

    hipMemsetAsync(d_ws, 0, 3440000 * sizeof(float), stream);

    k_prep_w<<<(149504 + 255) / 256, 256, 0, stream>>>(e1W, e2W, c1W, c2W, n1W, n2W, wb);
    k_fold<<<128, 256, 0, stream>>>(e1W, rW, rB, wb, bc);
    k_prep_h<<<(NN * 128 + 255) / 256, 256, 0, stream>>>(h, hb);
    k_node_pre<<<(NN + 255) / 256, 256, 0, stream>>>(x, cw, csum, pool);

    if (ws_size >= need) {
        k_prep_attrT<<<(NN * 256 + 255) / 256, 256, 0, stream>>>(attr, attrT);
        k_hw<<<NN / 32, 256, 0, stream>>>(hb, wb, H12);
        k_radial<<<NE / 64, 256, 0, stream>>>(x, row, col, attrT, cw, wb, bc, e1p);
        k_edge_split<<<NE / 32, 256, 0, stream>>>(x, row, col, H12, e1p, wb,
                                                  e1B, e2B, aW, aB, c1B, c2B,
                                                  csum, pool, xacc, agg, cntr, cntc);
    } else {
        k_edge_fused<<<NE / 32, 256, 0, stream>>>(x, row, col, attr, cw, hb, wb,
                                                  e1B, e2B, aW, aB, c1B, c2B,
                                                  bc, csum, pool, xacc, agg, cntr, cntc);
    }

    float* outh = (float*)d_out;
    float* outx = outh + NN * 128;
    k_node_post<<<NN / 32, 256, 0, stream>>>(h, x, wb, n1B, n2B, lng, lnb,
                                             agg, cntc, xacc, cntr, outh, outx);
}